// Round 1
// baseline (689.073 us; speedup 1.0000x reference)
//
#include <hip/hip_runtime.h>

// ---------------- constants ----------------
#define BB   512   // batch
#define SS   256   // seq len
#define EE   128   // emb dim
#define HH   128   // per-dir hidden
#define GG   512   // 4*H gates
#define LL   59    // labels
#define STARTL 57
#define STOPL  58

typedef float  f32x4  __attribute__((ext_vector_type(4)));
typedef short  bf16x8 __attribute__((ext_vector_type(8)));
typedef short  s16x4  __attribute__((ext_vector_type(4)));

__device__ __forceinline__ short f2bf(float f) {
    unsigned u = __float_as_uint(f);
    u += 0x7FFFu + ((u >> 16) & 1u);   // RNE
    return (short)(u >> 16);
}
__device__ __forceinline__ float sigf(float x) {
    float e = __builtin_amdgcn_exp2f(-1.44269504f * x);
    return __builtin_amdgcn_rcpf(1.0f + e);
}
__device__ __forceinline__ float tanhf_(float x) {
    float e = __builtin_amdgcn_exp2f(2.88539008f * x);
    return 1.0f - 2.0f * __builtin_amdgcn_rcpf(e + 1.0f);
}
__device__ __forceinline__ float wmax64(float v) {
    #pragma unroll
    for (int o = 32; o; o >>= 1) v = fmaxf(v, __shfl_xor(v, o));
    return v;
}
__device__ __forceinline__ float wsum64(float v) {
    #pragma unroll
    for (int o = 32; o; o >>= 1) v += __shfl_xor(v, o);
    return v;
}

// ---------------- kernel 1: persistent BiLSTM ----------------
// grid = 64 blocks (32 batch-tiles x 2 dirs), 512 threads (8 waves).
// Wave w owns hidden cols [16w,16w+16) for ALL 4 gate types -> c/h update is
// register-local. Weight B-frags (bf16) pinned in VGPRs. h/emb tiles staged in
// LDS chunk layout [c][m][8] (2-way-conflict-optimal ds_read_b128 A-frags).
__global__ __launch_bounds__(512, 2) void lstm_k(
    const int* __restrict__ x, const float* __restrict__ embed,
    const float* __restrict__ Wih_f, const float* __restrict__ Whh_f,
    const float* __restrict__ bih_f, const float* __restrict__ bhh_f,
    const float* __restrict__ Wih_b, const float* __restrict__ Whh_b,
    const float* __restrict__ bih_b, const float* __restrict__ bhh_b,
    const float* __restrict__ h0, const float* __restrict__ c0,
    unsigned short* __restrict__ hcat)
{
    const int tid = threadIdx.x;
    const int w  = tid >> 6;          // wave 0..7
    const int l  = tid & 63;
    const int qd = l >> 4;            // quad 0..3
    const int n  = l & 15;            // 0..15
    const int dir   = blockIdx.x & 1;
    const int b0    = (blockIdx.x >> 1) * 16;

    const float* Wih = dir ? Wih_b : Wih_f;
    const float* Whh = dir ? Whh_b : Whh_f;
    const float* bih = dir ? bih_b : bih_f;
    const float* bhh = dir ? bhh_b : bhh_f;

    __shared__ short hbuf[2][2048];   // [c 0..15][m 0..15][8] bf16
    __shared__ short ebuf[2][2048];

    // --- load weight fragments (held in VGPRs for entire kernel) ---
    bf16x8 fh[4][4], fx[4][4];        // [gate][kstep]
    float bias[4];
    #pragma unroll
    for (int g = 0; g < 4; ++g) {
        const int row = g * 128 + 16 * w + n;     // gate row
        bias[g] = bih[row] + bhh[row];
        #pragma unroll
        for (int kk = 0; kk < 4; ++kk) {
            const float* ph = Whh + (size_t)row * 128 + kk * 32 + qd * 8;
            const float* px = Wih + (size_t)row * 128 + kk * 32 + qd * 8;
            bf16x8 vh, vx;
            #pragma unroll
            for (int j = 0; j < 8; ++j) { vh[j] = f2bf(ph[j]); vx[j] = f2bf(px[j]); }
            fh[g][kk] = vh; fx[g][kk] = vx;
        }
    }

    // --- c state: 4 cells/lane: batch rows qd*4+r, hidden col 16w+n ---
    float cst[4];
    #pragma unroll
    for (int r = 0; r < 4; ++r)
        cst[r] = c0[((size_t)dir * BB + b0 + qd * 4 + r) * HH + 16 * w + n];

    // staging assignment: lane covers (m=l&15, 4-float k-group ek4=w*4+(l>>4))
    const int em   = l & 15;
    const int ek4  = w * 4 + (l >> 4);           // 0..31
    const int ek0  = ek4 * 4;
    const int eoff = ((ek4 >> 1) * 16 + em) * 8 + (ek4 & 1) * 4; // shorts

    {   // initial h0 -> hbuf[0], emb(t0) -> ebuf[0]
        const float4 hv = *(const float4*)(h0 + ((size_t)dir * BB + b0 + em) * HH + ek0);
        s16x4 hs = { f2bf(hv.x), f2bf(hv.y), f2bf(hv.z), f2bf(hv.w) };
        *(s16x4*)&hbuf[0][eoff] = hs;
        const int te0 = dir ? (SS - 1) : 0;
        const int xi  = x[(b0 + em) * SS + te0];
        const float4 ev = *(const float4*)(embed + (size_t)xi * EE + ek0);
        s16x4 es = { f2bf(ev.x), f2bf(ev.y), f2bf(ev.z), f2bf(ev.w) };
        *(s16x4*)&ebuf[0][eoff] = es;
    }
    __syncthreads();

    const int hid = 16 * w + n;
    const int hc  = hid >> 3, ho = hid & 7;

    for (int ts = 0; ts < SS; ++ts) {
        const int cur = ts & 1, nxt = cur ^ 1;
        const int te  = dir ? (SS - 1 - ts) : ts;

        // prefetch embedding for next step (global, latency overlapped)
        const int tn  = (ts < SS - 1) ? ts + 1 : ts;
        const int ten = dir ? (SS - 1 - tn) : tn;
        const int xi  = x[(b0 + em) * SS + ten];
        const float4 pf = *(const float4*)(embed + (size_t)xi * EE + ek0);

        // A fragments from LDS
        bf16x8 ah[4], ax[4];
        #pragma unroll
        for (int kk = 0; kk < 4; ++kk) {
            ah[kk] = *(const bf16x8*)&hbuf[cur][((kk * 4 + qd) * 16 + n) * 8];
            ax[kk] = *(const bf16x8*)&ebuf[cur][((kk * 4 + qd) * 16 + n) * 8];
        }

        f32x4 acc[4] = { {0,0,0,0}, {0,0,0,0}, {0,0,0,0}, {0,0,0,0} };
        #pragma unroll
        for (int kk = 0; kk < 4; ++kk) {
            #pragma unroll
            for (int g = 0; g < 4; ++g) {
                acc[g] = __builtin_amdgcn_mfma_f32_16x16x32_bf16(ah[kk], fh[g][kk], acc[g], 0, 0, 0);
                acc[g] = __builtin_amdgcn_mfma_f32_16x16x32_bf16(ax[kk], fx[g][kk], acc[g], 0, 0, 0);
            }
        }

        // store embedding prefetch into next buffer
        { s16x4 es = { f2bf(pf.x), f2bf(pf.y), f2bf(pf.z), f2bf(pf.w) };
          *(s16x4*)&ebuf[nxt][eoff] = es; }

        // nonlinearities + state update + h stores
        #pragma unroll
        for (int r = 0; r < 4; ++r) {
            const float iv = sigf(acc[0][r] + bias[0]);
            const float fv = sigf(acc[1][r] + bias[1]);
            const float gv = tanhf_(acc[2][r] + bias[2]);
            const float ov = sigf(acc[3][r] + bias[3]);
            const float cc = fv * cst[r] + iv * gv;
            cst[r] = cc;
            const float hv = ov * tanhf_(cc);
            const short hb = f2bf(hv);
            const int m = qd * 4 + r;
            hbuf[nxt][(hc * 16 + m) * 8 + ho] = hb;
            hcat[((size_t)(b0 + m) * SS + te) * 256 + dir * 128 + hid] = (unsigned short)hb;
        }
        __syncthreads();
    }
}

// ---------------- kernel 2: feats = hcat @ Wout^T + bout ----------------
// M = B*S = 131072 rows, N = 64 (59 padded), K = 256. One wave per 16-row tile.
__global__ __launch_bounds__(256, 2) void feat_k(
    const unsigned short* __restrict__ hcat, const float* __restrict__ Wout,
    const float* __restrict__ bout, float* __restrict__ feats)
{
    const int tid = threadIdx.x, w = tid >> 6, l = tid & 63, qd = l >> 4, n = l & 15;
    const size_t m0 = ((size_t)blockIdx.x * 4 + w) * 16;

    bf16x8 af[8];
    #pragma unroll
    for (int kk = 0; kk < 8; ++kk)
        af[kk] = *(const bf16x8*)(hcat + (m0 + n) * 256 + kk * 32 + qd * 8);

    f32x4 acc[4] = { {0,0,0,0}, {0,0,0,0}, {0,0,0,0}, {0,0,0,0} };
    #pragma unroll
    for (int nt = 0; nt < 4; ++nt) {
        const int col = nt * 16 + n;
        #pragma unroll
        for (int kk = 0; kk < 8; ++kk) {
            bf16x8 bfr = (bf16x8)0;
            if (col < LL) {
                const float* p = Wout + (size_t)col * 256 + kk * 32 + qd * 8;
                #pragma unroll
                for (int j = 0; j < 8; ++j) bfr[j] = f2bf(p[j]);
            }
            acc[nt] = __builtin_amdgcn_mfma_f32_16x16x32_bf16(af[kk], bfr, acc[nt], 0, 0, 0);
        }
    }
    #pragma unroll
    for (int nt = 0; nt < 4; ++nt) {
        const int col = nt * 16 + n;
        const float bv = (col < LL) ? bout[col] : 0.0f;
        #pragma unroll
        for (int r = 0; r < 4; ++r)
            feats[(m0 + qd * 4 + r) * 64 + col] = acc[nt][r] + bv;
    }
}

// ---------------- kernel 3: CRF forward + gold + reduce ----------------
// One wave per batch element. exp(trans) rows pinned in 59 VGPRs/lane;
// inner dot = 59 x (v_readlane + v_fmac). Feats prefetched 4 steps ahead.
__global__ __launch_bounds__(256, 2) void crf_k(
    const float* __restrict__ feats, const int* __restrict__ y,
    const float* __restrict__ trans, float* __restrict__ out)
{
    const int tid = threadIdx.x, w = tid >> 6, j = tid & 63;
    const int b = blockIdx.x * 4 + w;
    const size_t bS = (size_t)b * SS;
    const bool valid = (j < LL);
    const int  jr = valid ? j : (LL - 1);

    float etr[LL];
    #pragma unroll
    for (int i = 0; i < LL; ++i) {
        const float t = trans[jr * LL + i];
        etr[i] = valid ? __builtin_amdgcn_exp2f(t * 1.44269504f) : 0.0f;
    }

    float alpha = valid ? ((j == STARTL) ? 0.0f : -10000.0f) : -1e30f;

    float fb[4];
    #pragma unroll
    for (int q = 0; q < 4; ++q) fb[q] = feats[(bS + q) * 64 + j];

    for (int t0 = 0; t0 < SS; t0 += 4) {
        float fn[4] = {0, 0, 0, 0};
        if (t0 + 4 < SS) {
            #pragma unroll
            for (int q = 0; q < 4; ++q) fn[q] = feats[(bS + t0 + 4 + q) * 64 + j];
        }
        #pragma unroll
        for (int u = 0; u < 4; ++u) {
            const float m  = wmax64(alpha);
            const float ea = valid ? __builtin_amdgcn_exp2f((alpha - m) * 1.44269504f) : 0.0f;
            float dot = 0.0f;
            #pragma unroll
            for (int i = 0; i < LL; ++i)
                dot += etr[i] * __uint_as_float(
                    __builtin_amdgcn_readlane(__float_as_uint(ea), i));
            const float na = fb[u] + m + __builtin_amdgcn_logf(dot) * 0.69314718f;
            alpha = valid ? na : -1e30f;
        }
        #pragma unroll
        for (int q = 0; q < 4; ++q) fb[q] = fn[q];
    }

    // forward score: logsumexp(alpha + trans[STOP, :])
    const float v  = valid ? (alpha + trans[STOPL * LL + jr]) : -1e30f;
    const float m2 = wmax64(v);
    const float s  = wsum64(valid ? __builtin_amdgcn_exp2f((v - m2) * 1.44269504f) : 0.0f);
    const float fwd = m2 + __builtin_amdgcn_logf(s) * 0.69314718f;

    // gold path score (lanes parallel over t)
    float g = 0.0f;
    #pragma unroll
    for (int q = 0; q < 4; ++q) {
        const int t  = q * 64 + j;
        const int yt = y[bS + t];
        const int yp = t ? y[bS + t - 1] : STARTL;
        g += feats[(bS + t) * 64 + yt] + trans[yt * LL + yp];
    }
    g = wsum64(g);

    if (j == 0) {
        g += trans[STOPL * LL + y[bS + SS - 1]];
        atomicAdd(out, fwd - g);
    }
}

// ---------------- launcher ----------------
extern "C" void kernel_launch(void* const* d_in, const int* in_sizes, int n_in,
                              void* d_out, int out_size, void* d_ws, size_t ws_size,
                              hipStream_t stream)
{
    (void)in_sizes; (void)n_in; (void)out_size; (void)ws_size;
    const int*   x      = (const int*)  d_in[0];
    const int*   y      = (const int*)  d_in[1];
    const float* embed  = (const float*)d_in[2];
    const float* Wih_f  = (const float*)d_in[3];
    const float* Whh_f  = (const float*)d_in[4];
    const float* bih_f  = (const float*)d_in[5];
    const float* bhh_f  = (const float*)d_in[6];
    const float* Wih_b  = (const float*)d_in[7];
    const float* Whh_b  = (const float*)d_in[8];
    const float* bih_b  = (const float*)d_in[9];
    const float* bhh_b  = (const float*)d_in[10];
    const float* Wout   = (const float*)d_in[11];
    const float* bout   = (const float*)d_in[12];
    const float* trans  = (const float*)d_in[13];
    const float* h0     = (const float*)d_in[14];
    const float* c0     = (const float*)d_in[15];

    unsigned short* hcat  = (unsigned short*)d_ws;                       // 64 MiB bf16
    float*          feats = (float*)((char*)d_ws + (size_t)BB * SS * 256 * 2); // 32 MiB f32

    hipMemsetAsync(d_out, 0, sizeof(float), stream);
    lstm_k<<<64, 512, 0, stream>>>(x, embed, Wih_f, Whh_f, bih_f, bhh_f,
                                   Wih_b, Whh_b, bih_b, bhh_b, h0, c0, hcat);
    feat_k<<<2048, 256, 0, stream>>>(hcat, Wout, bout, feats);
    crf_k<<<BB / 4, 256, 0, stream>>>(feats, y, trans, (float*)d_out);
}

// Round 2
// 575.065 us; speedup vs baseline: 1.1983x; 1.1983x over previous
//
#include <hip/hip_runtime.h>

// ---------------- constants ----------------
#define BB   512   // batch
#define SS   256   // seq len
#define EE   128   // emb dim
#define HH   128   // per-dir hidden
#define LL   59    // labels
#define STARTL 57
#define STOPL  58
#define VOCAB 50000

typedef float  f32x4  __attribute__((ext_vector_type(4)));
typedef short  bf16x8 __attribute__((ext_vector_type(8)));
typedef short  s16x4  __attribute__((ext_vector_type(4)));

__device__ __forceinline__ short f2bf(float f) {
    unsigned u = __float_as_uint(f);
    u += 0x7FFFu + ((u >> 16) & 1u);   // RNE
    return (short)(u >> 16);
}
__device__ __forceinline__ float sigf(float x) {
    float e = __builtin_amdgcn_exp2f(-1.44269504f * x);
    return __builtin_amdgcn_rcpf(1.0f + e);
}
__device__ __forceinline__ float tanhf_(float x) {
    float e = __builtin_amdgcn_exp2f(2.88539008f * x);
    return 1.0f - 2.0f * __builtin_amdgcn_rcpf(e + 1.0f);
}
__device__ __forceinline__ float wmax64(float v) {
    #pragma unroll
    for (int o = 32; o; o >>= 1) v = fmaxf(v, __shfl_xor(v, o));
    return v;
}
__device__ __forceinline__ float wsum64(float v) {
    #pragma unroll
    for (int o = 32; o; o >>= 1) v += __shfl_xor(v, o);
    return v;
}
// async global->LDS, 16B per lane; LDS dest = wave-uniform base + lane*16
__device__ __forceinline__ void glds16(const void* g, void* l) {
    __builtin_amdgcn_global_load_lds(
        (const __attribute__((address_space(1))) unsigned int*)g,
        (__attribute__((address_space(3))) unsigned int*)l, 16, 0, 0);
}

// ---------------- kernel 0: embed f32 -> bf16 table ----------------
__global__ __launch_bounds__(256) void conv_k(const float* __restrict__ embed,
                                              unsigned short* __restrict__ ebf)
{
    const int N4 = VOCAB * EE / 4;
    for (int i = blockIdx.x * blockDim.x + threadIdx.x; i < N4;
         i += gridDim.x * blockDim.x) {
        float4 v = ((const float4*)embed)[i];
        s16x4 s = { f2bf(v.x), f2bf(v.y), f2bf(v.z), f2bf(v.w) };
        ((s16x4*)ebf)[i] = s;
    }
}

// ---------------- kernel 1: persistent BiLSTM + fused projection ----------------
// grid = 64 blocks (32 batch-tiles x 2 dirs), 512 threads (8 waves).
// Waves 0-3 stage next-step embedding tile via global_load_lds (bf16 table,
// x-tile pre-staged in LDS -> no dependent gather chain on critical path).
// Waves 4-7 project the PREVIOUS step's h (== this step's A-fragment ah)
// against their Wout half and store f32 partial feats (feat_k eliminated).
__global__ __launch_bounds__(512, 2) void lstm_k(
    const int* __restrict__ x, const unsigned short* __restrict__ ebf,
    const float* __restrict__ Wih_f, const float* __restrict__ Whh_f,
    const float* __restrict__ bih_f, const float* __restrict__ bhh_f,
    const float* __restrict__ Wih_b, const float* __restrict__ Whh_b,
    const float* __restrict__ bih_b, const float* __restrict__ bhh_b,
    const float* __restrict__ h0, const float* __restrict__ c0,
    const float* __restrict__ Wout,
    float* __restrict__ fpF, float* __restrict__ fpB)
{
    const int tid = threadIdx.x;
    const int w  = tid >> 6;          // wave 0..7
    const int l  = tid & 63;
    const int qd = l >> 4;            // quad 0..3
    const int n  = l & 15;            // 0..15
    const int dir   = blockIdx.x & 1;
    const int b0    = (blockIdx.x >> 1) * 16;

    const float* Wih = dir ? Wih_b : Wih_f;
    const float* Whh = dir ? Whh_b : Whh_f;
    const float* bih = dir ? bih_b : bih_f;
    const float* bhh = dir ? bhh_b : bhh_f;
    float* fp = dir ? fpB : fpF;

    __shared__ short hbuf[2][2048];   // [octet 0..15][m 0..15][8] bf16
    __shared__ short ebuf[2][2048];
    __shared__ int   xsh[16 * SS];    // [m][t]

    // --- stage x tile (rows contiguous: (b0+m)*SS + t == b0*SS + m*SS + t) ---
    {
        const int4* xg = (const int4*)(x + (size_t)b0 * SS);
        int4* xs = (int4*)xsh;
        xs[tid]       = xg[tid];
        xs[tid + 512] = xg[tid + 512];
    }

    // --- weight fragments (held in VGPRs for entire kernel) ---
    bf16x8 fh[4][4], fx[4][4];        // [gate][kstep]
    float bias[4];
    #pragma unroll
    for (int g = 0; g < 4; ++g) {
        const int row = g * 128 + 16 * w + n;     // gate row
        bias[g] = bih[row] + bhh[row];
        #pragma unroll
        for (int kk = 0; kk < 4; ++kk) {
            const float* ph = Whh + (size_t)row * 128 + kk * 32 + qd * 8;
            const float* px = Wih + (size_t)row * 128 + kk * 32 + qd * 8;
            bf16x8 vh, vx;
            #pragma unroll
            for (int j = 0; j < 8; ++j) { vh[j] = f2bf(ph[j]); vx[j] = f2bf(px[j]); }
            fh[g][kk] = vh; fx[g][kk] = vx;
        }
    }
    // --- Wout fragment (dir half), used by waves 4-7; nt = w&3 ---
    bf16x8 wb[4];
    {
        const int col = (w & 3) * 16 + n;         // label column
        #pragma unroll
        for (int kk = 0; kk < 4; ++kk) {
            bf16x8 v = (bf16x8)0;
            if (col < LL) {
                const float* p = Wout + (size_t)col * 256 + dir * 128 + kk * 32 + qd * 8;
                #pragma unroll
                for (int j = 0; j < 8; ++j) v[j] = f2bf(p[j]);
            }
            wb[kk] = v;
        }
    }

    // --- c state: 4 cells/lane: batch rows qd*4+r, hidden col 16w+n ---
    float cst[4];
    #pragma unroll
    for (int r = 0; r < 4; ++r)
        cst[r] = c0[((size_t)dir * BB + b0 + qd * 4 + r) * HH + 16 * w + n];

    // h0 -> hbuf[0] (f32 path, once)
    {
        const int em  = l & 15;
        const int ek4 = w * 4 + (l >> 4);        // 4-float k-group 0..31
        const float4 hv = *(const float4*)(h0 + ((size_t)dir * BB + b0 + em) * HH + ek4 * 4);
        s16x4 hs = { f2bf(hv.x), f2bf(hv.y), f2bf(hv.z), f2bf(hv.w) };
        *(s16x4*)&hbuf[0][((ek4 >> 1) * 16 + em) * 8 + (ek4 & 1) * 4] = hs;
    }
    __syncthreads();   // xsh + hbuf[0] visible

    // issue ebuf[0] staging (waves 0-3): lane -> (m = l&15, octet = w*4 + (l>>4))
    if (w < 4) {
        const int te0 = dir ? (SS - 1) : 0;
        const int xi  = xsh[(l & 15) * SS + te0];
        glds16(ebf + (size_t)xi * EE + (w * 4 + (l >> 4)) * 8, &ebuf[0][w * 512]);
    }
    __syncthreads();   // barrier drain completes the DMA

    const int hid = 16 * w + n;
    const int hc  = hid >> 3, ho = hid & 7;

    for (int ts = 0; ts < SS; ++ts) {
        const int cur = ts & 1, nxt = cur ^ 1;
        const int te  = dir ? (SS - 1 - ts) : ts;

        // stage next embedding tile (waves 0-3); full step to complete
        if (w < 4 && ts + 1 < SS) {
            const int ten = dir ? (SS - 2 - ts) : (ts + 1);
            const int xi  = xsh[(l & 15) * SS + ten];
            glds16(ebf + (size_t)xi * EE + (w * 4 + (l >> 4)) * 8, &ebuf[nxt][w * 512]);
        }

        // A fragments from LDS (ah == previous step's h tile, full K=128)
        bf16x8 ah[4], ax[4];
        #pragma unroll
        for (int kk = 0; kk < 4; ++kk) {
            ah[kk] = *(const bf16x8*)&hbuf[cur][((kk * 4 + qd) * 16 + n) * 8];
            ax[kk] = *(const bf16x8*)&ebuf[cur][((kk * 4 + qd) * 16 + n) * 8];
        }

        f32x4 acc[4] = { {0,0,0,0}, {0,0,0,0}, {0,0,0,0}, {0,0,0,0} };
        #pragma unroll
        for (int kk = 0; kk < 4; ++kk) {
            #pragma unroll
            for (int g = 0; g < 4; ++g) {
                acc[g] = __builtin_amdgcn_mfma_f32_16x16x32_bf16(ah[kk], fh[g][kk], acc[g], 0, 0, 0);
                acc[g] = __builtin_amdgcn_mfma_f32_16x16x32_bf16(ax[kk], fx[g][kk], acc[g], 0, 0, 0);
            }
        }

        // fused projection of h_{ts-1} (waves 4-7; reuses ah)
        if (w >= 4 && ts > 0) {
            f32x4 pa = {0, 0, 0, 0};
            #pragma unroll
            for (int kk = 0; kk < 4; ++kk)
                pa = __builtin_amdgcn_mfma_f32_16x16x32_bf16(ah[kk], wb[kk], pa, 0, 0, 0);
            const int tep = dir ? (SS - ts) : (ts - 1);
            #pragma unroll
            for (int r = 0; r < 4; ++r)
                fp[((size_t)(b0 + qd * 4 + r) * SS + tep) * 64 + (w & 3) * 16 + n] = pa[r];
        }

        // nonlinearities + state update + h stores
        #pragma unroll
        for (int r = 0; r < 4; ++r) {
            const float iv = sigf(acc[0][r] + bias[0]);
            const float fv = sigf(acc[1][r] + bias[1]);
            const float gv = tanhf_(acc[2][r] + bias[2]);
            const float ov = sigf(acc[3][r] + bias[3]);
            const float cc = fv * cst[r] + iv * gv;
            cst[r] = cc;
            const float hv = ov * tanhf_(cc);
            hbuf[nxt][(hc * 16 + qd * 4 + r) * 8 + ho] = f2bf(hv);
        }
        __syncthreads();
    }

    // epilogue: project final h (in hbuf[SS & 1] == hbuf[0])
    if (w >= 4) {
        f32x4 pa = {0, 0, 0, 0};
        #pragma unroll
        for (int kk = 0; kk < 4; ++kk) {
            bf16x8 a = *(const bf16x8*)&hbuf[SS & 1][((kk * 4 + qd) * 16 + n) * 8];
            pa = __builtin_amdgcn_mfma_f32_16x16x32_bf16(a, wb[kk], pa, 0, 0, 0);
        }
        const int tep = dir ? 0 : (SS - 1);
        #pragma unroll
        for (int r = 0; r < 4; ++r)
            fp[((size_t)(b0 + qd * 4 + r) * SS + tep) * 64 + (w & 3) * 16 + n] = pa[r];
    }
}

// ---------------- kernel 2: CRF forward + gold + reduce ----------------
// One wave per batch element. exp(trans) rows pinned in 59 VGPRs/lane.
// Per-step offset K via 2 readlanes (no shuffle tree); dot in 4 accumulators.
__global__ __launch_bounds__(256, 2) void crf_k(
    const float* __restrict__ fpF, const float* __restrict__ fpB,
    const float* __restrict__ bout, const int* __restrict__ y,
    const float* __restrict__ trans, float* __restrict__ out)
{
    const int tid = threadIdx.x, w = tid >> 6, j = tid & 63;
    const int b = blockIdx.x * 4 + w;
    const size_t bS = (size_t)b * SS;
    const bool valid = (j < LL);
    const int  jr = valid ? j : (LL - 1);

    float etr[LL];
    #pragma unroll
    for (int i = 0; i < LL; ++i) {
        const float t = trans[jr * LL + i];
        etr[i] = valid ? __builtin_amdgcn_exp2f(t * 1.44269504f) : 0.0f;
    }
    const float bo = valid ? bout[jr] : 0.0f;

    float alpha = valid ? ((j == STARTL) ? 0.0f : -10000.0f) : -1e30f;

    float fF[4], fB[4];
    #pragma unroll
    for (int q = 0; q < 4; ++q) {
        fF[q] = fpF[(bS + q) * 64 + j];
        fB[q] = fpB[(bS + q) * 64 + j];
    }

    for (int t0 = 0; t0 < SS; t0 += 4) {
        float nF[4] = {0,0,0,0}, nB[4] = {0,0,0,0};
        if (t0 + 4 < SS) {
            #pragma unroll
            for (int q = 0; q < 4; ++q) {
                nF[q] = fpF[(bS + t0 + 4 + q) * 64 + j];
                nB[q] = fpB[(bS + t0 + 4 + q) * 64 + j];
            }
        }
        #pragma unroll
        for (int u = 0; u < 4; ++u) {
            // running offset: max over two always-representative lanes
            const float K = fmaxf(
                __uint_as_float(__builtin_amdgcn_readlane(__float_as_uint(alpha), 1)),
                __uint_as_float(__builtin_amdgcn_readlane(__float_as_uint(alpha), STARTL)));
            const float ea = __builtin_amdgcn_exp2f((alpha - K) * 1.44269504f);
            float d0 = 0.0f, d1 = 0.0f, d2 = 0.0f, d3 = 0.0f;
            #pragma unroll
            for (int i = 0; i < LL; i += 4) {
                d0 += etr[i] * __uint_as_float(__builtin_amdgcn_readlane(__float_as_uint(ea), i));
                if (i + 1 < LL) d1 += etr[i+1] * __uint_as_float(__builtin_amdgcn_readlane(__float_as_uint(ea), i+1));
                if (i + 2 < LL) d2 += etr[i+2] * __uint_as_float(__builtin_amdgcn_readlane(__float_as_uint(ea), i+2));
                if (i + 3 < LL) d3 += etr[i+3] * __uint_as_float(__builtin_amdgcn_readlane(__float_as_uint(ea), i+3));
            }
            const float dot = (d0 + d1) + (d2 + d3);
            alpha = (fF[u] + fB[u] + bo) + K +
                    0.69314718f * __builtin_amdgcn_logf(dot);
        }
        #pragma unroll
        for (int q = 0; q < 4; ++q) { fF[q] = nF[q]; fB[q] = nB[q]; }
    }

    // forward score: exact logsumexp(alpha + trans[STOP, :])
    const float v  = alpha + trans[STOPL * LL + jr];   // invalid lanes: alpha = -inf
    const float m2 = wmax64(v);
    const float s  = wsum64(__builtin_amdgcn_exp2f((v - m2) * 1.44269504f));
    const float fwd = m2 + 0.69314718f * __builtin_amdgcn_logf(s);

    // gold path score (lanes parallel over t)
    float g = 0.0f;
    #pragma unroll
    for (int q = 0; q < 4; ++q) {
        const int t  = q * 64 + j;
        const int yt = y[bS + t];
        const int yp = t ? y[bS + t - 1] : STARTL;
        g += fpF[(bS + t) * 64 + yt] + fpB[(bS + t) * 64 + yt] + bout[yt]
           + trans[yt * LL + yp];
    }
    g = wsum64(g);

    if (j == 0) {
        g += trans[STOPL * LL + y[bS + SS - 1]];
        atomicAdd(out, fwd - g);
    }
}

// ---------------- launcher ----------------
extern "C" void kernel_launch(void* const* d_in, const int* in_sizes, int n_in,
                              void* d_out, int out_size, void* d_ws, size_t ws_size,
                              hipStream_t stream)
{
    (void)in_sizes; (void)n_in; (void)out_size; (void)ws_size;
    const int*   x      = (const int*)  d_in[0];
    const int*   y      = (const int*)  d_in[1];
    const float* embed  = (const float*)d_in[2];
    const float* Wih_f  = (const float*)d_in[3];
    const float* Whh_f  = (const float*)d_in[4];
    const float* bih_f  = (const float*)d_in[5];
    const float* bhh_f  = (const float*)d_in[6];
    const float* Wih_b  = (const float*)d_in[7];
    const float* Whh_b  = (const float*)d_in[8];
    const float* bih_b  = (const float*)d_in[9];
    const float* bhh_b  = (const float*)d_in[10];
    const float* Wout   = (const float*)d_in[11];
    const float* bout   = (const float*)d_in[12];
    const float* trans  = (const float*)d_in[13];
    const float* h0     = (const float*)d_in[14];
    const float* c0     = (const float*)d_in[15];

    unsigned short* ebf = (unsigned short*)d_ws;                        // 12.8 MiB bf16
    float* fpF = (float*)((char*)d_ws + (size_t)16 * 1024 * 1024);      // 32 MiB f32
    float* fpB = (float*)((char*)d_ws + (size_t)48 * 1024 * 1024);      // 32 MiB f32

    hipMemsetAsync(d_out, 0, sizeof(float), stream);
    conv_k<<<2048, 256, 0, stream>>>(embed, ebf);
    lstm_k<<<64, 512, 0, stream>>>(x, ebf, Wih_f, Whh_f, bih_f, bhh_f,
                                   Wih_b, Whh_b, bih_b, bhh_b, h0, c0,
                                   Wout, fpF, fpB);
    crf_k<<<BB / 4, 256, 0, stream>>>(fpF, fpB, bout, y, trans, (float*)d_out);
}